// Round 5
// baseline (396.242 us; speedup 1.0000x reference)
//
#include <hip/hip_runtime.h>

typedef short short8 __attribute__((ext_vector_type(8)));
typedef short short4_ __attribute__((ext_vector_type(4)));
typedef float f32x4 __attribute__((ext_vector_type(4)));

static __device__ __forceinline__ short f2bf(float f) {
  union { float f; unsigned u; } x; x.f = f;
  unsigned r = x.u + 0x7fffu + ((x.u >> 16) & 1u);
  return (short)(r >> 16);
}

// ---------------- kernel 1: cast q,k,v f32 -> bf16 ----------------
__global__ __launch_bounds__(256) void cast_qkv(
    const float* __restrict__ q, const float* __restrict__ k, const float* __restrict__ v,
    short* __restrict__ xq, short* __restrict__ xk, short* __restrict__ xv) {
  int z = blockIdx.z;
  const float* s = (z == 0) ? q : (z == 1) ? k : v;
  short* d = (z == 0) ? xq : (z == 1) ? xk : xv;
  int i = (blockIdx.x * 256 + threadIdx.x) * 4;
  float4 f = *(const float4*)(s + i);
  short4_ o;
  o[0] = f2bf(f.x); o[1] = f2bf(f.y); o[2] = f2bf(f.z); o[3] = f2bf(f.w);
  *(short4_*)(d + i) = o;
}

// ------------- kernel 2: pack W (H,D,DK) f32 -> Bt (H*DK, D) bf16 -------------
__global__ __launch_bounds__(256) void pack_w(
    const float* __restrict__ wq, const float* __restrict__ wk, const float* __restrict__ wv,
    short* __restrict__ oq, short* __restrict__ ok, short* __restrict__ ov) {
  int z = blockIdx.z;
  const float* W = (z == 0) ? wq : (z == 1) ? wk : wv;
  short* o = ((z == 0) ? oq : (z == 1) ? ok : ov) + (size_t)blockIdx.x * 1024;
  int c = blockIdx.x;
  int h = c >> 6, kk = c & 63;
  const float* src = W + (size_t)h * 65536 + kk;  // + d*64
  #pragma unroll
  for (int it = 0; it < 4; ++it) {
    int d = it * 256 + threadIdx.x;
    o[d] = f2bf(src[(size_t)d * 64]);
  }
}

// ------------- kernel 3: projection GEMM  C[4096][1024] = A[4096][1024] * Bt^T -------------
// 128x128 tile, BK=32, 4 waves, 16x16x32 bf16 MFMA, register-staged LDS.
__global__ __launch_bounds__(256) void proj_gemm(
    const short* __restrict__ xq, const short* __restrict__ xk, const short* __restrict__ xv,
    const short* __restrict__ wq, const short* __restrict__ wk, const short* __restrict__ wv,
    short* __restrict__ pq, short* __restrict__ pk, short* __restrict__ pv) {
  int z = blockIdx.z;
  const short* A  = (z == 0) ? xq : (z == 1) ? xk : xv;
  const short* Bt = (z == 0) ? wq : (z == 1) ? wk : wv;
  short* C        = (z == 0) ? pq : (z == 1) ? pk : pv;
  __shared__ __attribute__((aligned(16))) short As[128 * 32];
  __shared__ __attribute__((aligned(16))) short Bs[128 * 32];
  int t = threadIdx.x, l = t & 63, w = t >> 6;
  int wr = w >> 1, wc = w & 1;
  int lr = l & 15, lk = l >> 4;
  int bm0 = blockIdx.y * 128, bn0 = blockIdx.x * 128;
  const f32x4 Z = {0.f, 0.f, 0.f, 0.f};
  f32x4 acc[4][4];
  #pragma unroll
  for (int m = 0; m < 4; ++m)
    #pragma unroll
    for (int n = 0; n < 4; ++n) acc[m][n] = Z;

  int r0 = t >> 2, r1 = r0 + 64;
  int s0 = (t & 3) * 8;
  const short* gA0 = A + (size_t)(bm0 + r0) * 1024 + s0;
  const short* gA1 = A + (size_t)(bm0 + r1) * 1024 + s0;
  const short* gB0 = Bt + (size_t)(bn0 + r0) * 1024 + s0;
  const short* gB1 = Bt + (size_t)(bn0 + r1) * 1024 + s0;

  for (int kb = 0; kb < 1024; kb += 32) {
    short8 a0 = *(const short8*)(gA0 + kb);
    short8 a1 = *(const short8*)(gA1 + kb);
    short8 b0 = *(const short8*)(gB0 + kb);
    short8 b1 = *(const short8*)(gB1 + kb);
    *(short8*)(As + r0 * 32 + s0) = a0;
    *(short8*)(As + r1 * 32 + s0) = a1;
    *(short8*)(Bs + r0 * 32 + s0) = b0;
    *(short8*)(Bs + r1 * 32 + s0) = b1;
    __syncthreads();
    short8 a[4], bfr[4];
    #pragma unroll
    for (int m = 0; m < 4; ++m)
      a[m] = *(const short8*)(As + (wr * 64 + m * 16 + lr) * 32 + lk * 8);
    #pragma unroll
    for (int n = 0; n < 4; ++n)
      bfr[n] = *(const short8*)(Bs + (wc * 64 + n * 16 + lr) * 32 + lk * 8);
    #pragma unroll
    for (int m = 0; m < 4; ++m)
      #pragma unroll
      for (int n = 0; n < 4; ++n)
        acc[m][n] = __builtin_amdgcn_mfma_f32_16x16x32_bf16(a[m], bfr[n], acc[m][n], 0, 0, 0);
    __syncthreads();
  }
  #pragma unroll
  for (int m = 0; m < 4; ++m)
    #pragma unroll
    for (int n = 0; n < 4; ++n)
      #pragma unroll
      for (int i = 0; i < 4; ++i) {
        int r = bm0 + wr * 64 + m * 16 + lk * 4 + i;
        int cc = bn0 + wc * 64 + n * 16 + lr;
        C[(size_t)r * 1024 + cc] = f2bf(acc[m][n][i]);
      }
}

// ------------- kernel 4: V transpose  pv[b*N+n][h*64+dv] -> vt[hb][dv][n] -------------
__global__ __launch_bounds__(256) void vtrans(
    const short* __restrict__ pv, short* __restrict__ vt) {
  __shared__ short T[64 * 72];
  int t = threadIdx.x;
  int hb = blockIdx.y, h = hb >> 2, b = hb & 3;
  int n0 = blockIdx.x * 64;
  const short* src = pv + (size_t)b * 1048576 + (size_t)n0 * 1024 + h * 64;
  #pragma unroll
  for (int it = 0; it < 2; ++it) {
    int id = it * 256 + t;
    int row = id >> 3, seg = id & 7;
    *(short8*)(T + row * 72 + seg * 8) = *(const short8*)(src + (size_t)row * 1024 + seg * 8);
  }
  __syncthreads();
  short* dst = vt + (size_t)hb * 65536 + n0;
  #pragma unroll
  for (int it = 0; it < 2; ++it) {
    int id = it * 256 + t;
    int dv = id >> 3, seg = id & 7;
    short8 vv;
    #pragma unroll
    for (int jj = 0; jj < 8; ++jj) vv[jj] = T[(seg * 8 + jj) * 72 + dv];
    *(short8*)(dst + (size_t)dv * 1024 + seg * 8) = vv;
  }
}

// ------------- kernel 5: scores + softmax -> attn (f32, in d_out) -------------
// block: one (hb, 32-row q-tile). Full 32x1024 score rows in f32 LDS.
__global__ __launch_bounds__(256) void scores_softmax(
    const short* __restrict__ pq, const short* __restrict__ pk, float* __restrict__ dout) {
  __shared__ float Sc[32 * 1024];                       // 128 KB
  __shared__ __attribute__((aligned(16))) short Qs[32 * 72];
  __shared__ __attribute__((aligned(16))) short Ks[32 * 72];
  __shared__ float Mrow[32], Irow[32];
  int t = threadIdx.x, l = t & 63, w = t >> 6;
  int lr = l & 15, lk = l >> 4;
  int hb = blockIdx.y, h = hb >> 2, b = hb & 3;
  int q0 = blockIdx.x * 32;
  const short* Qg = pq + (size_t)b * 1048576 + h * 64;
  const short* Kg = pk + (size_t)b * 1048576 + h * 64;
  float* attnp = dout + 4194304 + (size_t)hb * 1048576 + (size_t)q0 * 1024;

  {  // stage Q tile [32][64]
    int row = t >> 3, seg = t & 7;
    *(short8*)(Qs + row * 72 + seg * 8) = *(const short8*)(Qg + (size_t)(q0 + row) * 1024 + seg * 8);
  }
  int rf = w >> 1, cf = w & 1;
  const f32x4 Z = {0.f, 0.f, 0.f, 0.f};
  for (int kc = 0; kc < 32; ++kc) {
    {  // stage K chunk [32][64]
      int row = t >> 3, seg = t & 7;
      *(short8*)(Ks + row * 72 + seg * 8) =
          *(const short8*)(Kg + (size_t)(kc * 32 + row) * 1024 + seg * 8);
    }
    __syncthreads();
    f32x4 acc = Z;
    short8 aq0 = *(const short8*)(Qs + (rf * 16 + lr) * 72 + lk * 8);
    short8 aq1 = *(const short8*)(Qs + (rf * 16 + lr) * 72 + 32 + lk * 8);
    short8 bk0 = *(const short8*)(Ks + (cf * 16 + lr) * 72 + lk * 8);
    short8 bk1 = *(const short8*)(Ks + (cf * 16 + lr) * 72 + 32 + lk * 8);
    acc = __builtin_amdgcn_mfma_f32_16x16x32_bf16(aq0, bk0, acc, 0, 0, 0);
    acc = __builtin_amdgcn_mfma_f32_16x16x32_bf16(aq1, bk1, acc, 0, 0, 0);
    #pragma unroll
    for (int i = 0; i < 4; ++i)
      Sc[(rf * 16 + lk * 4 + i) * 1024 + kc * 32 + cf * 16 + lr] = acc[i] * 0.125f;
    __syncthreads();
  }
  {  // row-wise max & sum: 8 threads per row
    int row = t >> 3, sub = t & 7;
    const float* Sr = Sc + row * 1024 + sub * 128;
    float mx = -1e30f;
    for (int j = 0; j < 128; ++j) mx = fmaxf(mx, Sr[j]);
    #pragma unroll
    for (int msk = 1; msk < 8; msk <<= 1) mx = fmaxf(mx, __shfl_xor(mx, msk, 64));
    float sm = 0.f;
    for (int j = 0; j < 128; ++j) sm += __expf(Sr[j] - mx);
    #pragma unroll
    for (int msk = 1; msk < 8; msk <<= 1) sm += __shfl_xor(sm, msk, 64);
    if (sub == 0) { Mrow[row] = mx; Irow[row] = 1.0f / sm; }
  }
  __syncthreads();
  #pragma unroll
  for (int it = 0; it < 16; ++it) {  // normalize + write attn (f32)
    int id = it * 256 + t;
    int row = id >> 7, seg = id & 127;
    float mx = Mrow[row], iv = Irow[row];
    const float* Sr = Sc + row * 1024 + seg * 8;
    float4 o0, o1;
    o0.x = __expf(Sr[0] - mx) * iv; o0.y = __expf(Sr[1] - mx) * iv;
    o0.z = __expf(Sr[2] - mx) * iv; o0.w = __expf(Sr[3] - mx) * iv;
    o1.x = __expf(Sr[4] - mx) * iv; o1.y = __expf(Sr[5] - mx) * iv;
    o1.z = __expf(Sr[6] - mx) * iv; o1.w = __expf(Sr[7] - mx) * iv;
    float* gp = attnp + (size_t)row * 1024 + seg * 8;
    *(float4*)gp = o0;
    *(float4*)(gp + 4) = o1;
  }
}

// ------------- kernel 6: out = P * V   (per (hb, 64-row n-tile)), attn read f32 -------------
__global__ __launch_bounds__(256) void pv_gemm(
    const float* __restrict__ attn_all, const short* __restrict__ vt, float* __restrict__ dout) {
  __shared__ __attribute__((aligned(16))) short Ps[64 * 40];
  __shared__ __attribute__((aligned(16))) short Vs[64 * 40];
  int t = threadIdx.x, l = t & 63, w = t >> 6;
  int lr = l & 15, lk = l >> 4;
  int hb = blockIdx.y, h = hb >> 2, b = hb & 3;
  int n0 = blockIdx.x * 64;
  const float* Pg = attn_all + (size_t)hb * 1048576 + (size_t)n0 * 1024;
  const short* Vg = vt + (size_t)hb * 65536;
  const f32x4 Z = {0.f, 0.f, 0.f, 0.f};
  f32x4 acc[4] = {Z, Z, Z, Z};
  int sr = t >> 2, ss = (t & 3) * 8;
  for (int kc = 0; kc < 1024; kc += 32) {
    float4 p0 = *(const float4*)(Pg + (size_t)sr * 1024 + kc + ss);
    float4 p1 = *(const float4*)(Pg + (size_t)sr * 1024 + kc + ss + 4);
    short8 ps;
    ps[0] = f2bf(p0.x); ps[1] = f2bf(p0.y); ps[2] = f2bf(p0.z); ps[3] = f2bf(p0.w);
    ps[4] = f2bf(p1.x); ps[5] = f2bf(p1.y); ps[6] = f2bf(p1.z); ps[7] = f2bf(p1.w);
    *(short8*)(Ps + sr * 40 + ss) = ps;
    *(short8*)(Vs + sr * 40 + ss) = *(const short8*)(Vg + (size_t)sr * 1024 + kc + ss);
    __syncthreads();
    short8 ap = *(const short8*)(Ps + (w * 16 + lr) * 40 + lk * 8);
    #pragma unroll
    for (int f = 0; f < 4; ++f) {
      short8 bv = *(const short8*)(Vs + (f * 16 + lr) * 40 + lk * 8);
      acc[f] = __builtin_amdgcn_mfma_f32_16x16x32_bf16(ap, bv, acc[f], 0, 0, 0);
    }
    __syncthreads();
  }
  #pragma unroll
  for (int f = 0; f < 4; ++f)
    #pragma unroll
    for (int i = 0; i < 4; ++i) {
      int row = n0 + w * 16 + lk * 4 + i;
      int dv = f * 16 + lr;
      dout[(size_t)b * 1048576 + (size_t)row * 1024 + h * 64 + dv] = acc[f][i];
    }
}

extern "C" void kernel_launch(void* const* d_in, const int* in_sizes, int n_in,
                              void* d_out, int out_size, void* d_ws, size_t ws_size,
                              hipStream_t stream) {
  // inputs are f32 (verified: rounds 3/4 bit-identical with runtime detection).
  const void* big[3] = {0, 0, 0};
  const void* small[3] = {0, 0, 0};
  int nb = 0, ns = 0;
  for (int i = 0; i < n_in && i < 6; ++i) {
    if (in_sizes[i] == 4194304) { if (nb < 3) big[nb++] = d_in[i]; }
    else                        { if (ns < 3) small[ns++] = d_in[i]; }
  }
  const float *q, *k, *v, *wq, *wk, *wv;
  if (nb == 3 && ns == 3) {
    q = (const float*)big[0]; k = (const float*)big[1]; v = (const float*)big[2];
    wq = (const float*)small[0]; wk = (const float*)small[1]; wv = (const float*)small[2];
  } else {
    q = (const float*)d_in[0]; k = (const float*)d_in[1]; v = (const float*)d_in[2];
    wq = (const float*)d_in[3]; wk = (const float*)d_in[4]; wv = (const float*)d_in[5];
  }
  // workspace layout (shorts): total 32,505,856 shorts = 65 MB
  short* W   = (short*)d_ws;
  short* xq  = W;
  short* xk  = W + 4194304;
  short* xv  = W + 8388608;
  short* wtq = W + 12582912;
  short* wtk = W + 13631488;
  short* wtv = W + 14680064;
  short* pq  = W + 15728640;
  short* pk  = W + 19922944;
  short* pv  = W + 24117248;
  short* vt  = W + 28311552;
  float* out = (float*)d_out;

  cast_qkv<<<dim3(4096, 1, 3), 256, 0, stream>>>(q, k, v, xq, xk, xv);
  pack_w<<<dim3(1024, 1, 3), 256, 0, stream>>>(wq, wk, wv, wtq, wtk, wtv);
  proj_gemm<<<dim3(8, 32, 3), 256, 0, stream>>>(xq, xk, xv, wtq, wtk, wtv, pq, pk, pv);
  vtrans<<<dim3(16, 64), 256, 0, stream>>>(pv, vt);
  scores_softmax<<<dim3(32, 64), 256, 0, stream>>>(pq, pk, out);
  pv_gemm<<<dim3(16, 64), 256, 0, stream>>>(out + 4194304, vt, out);
}

// Round 6
// 202.405 us; speedup vs baseline: 1.9577x; 1.9577x over previous
//
#include <hip/hip_runtime.h>

typedef short short8 __attribute__((ext_vector_type(8)));
typedef short short4_ __attribute__((ext_vector_type(4)));
typedef float f32x4 __attribute__((ext_vector_type(4)));

static __device__ __forceinline__ short f2bf(float f) {
  union { float f; unsigned u; } x; x.f = f;
  unsigned r = x.u + 0x7fffu + ((x.u >> 16) & 1u);
  return (short)(r >> 16);
}

// ---------------- kernel 1: cast q,k,v f32 -> bf16 ----------------
__global__ __launch_bounds__(256) void cast_qkv(
    const float* __restrict__ q, const float* __restrict__ k, const float* __restrict__ v,
    short* __restrict__ xq, short* __restrict__ xk, short* __restrict__ xv) {
  int z = blockIdx.z;
  const float* s = (z == 0) ? q : (z == 1) ? k : v;
  short* d = (z == 0) ? xq : (z == 1) ? xk : xv;
  int i = (blockIdx.x * 256 + threadIdx.x) * 4;
  float4 f = *(const float4*)(s + i);
  short4_ o;
  o[0] = f2bf(f.x); o[1] = f2bf(f.y); o[2] = f2bf(f.z); o[3] = f2bf(f.w);
  *(short4_*)(d + i) = o;
}

// ------------- kernel 2: pack W (H,D,DK) f32 -> Bt (H*DK, D) bf16 -------------
__global__ __launch_bounds__(256) void pack_w(
    const float* __restrict__ wq, const float* __restrict__ wk, const float* __restrict__ wv,
    short* __restrict__ oq, short* __restrict__ ok, short* __restrict__ ov) {
  int z = blockIdx.z;
  const float* W = (z == 0) ? wq : (z == 1) ? wk : wv;
  short* o = ((z == 0) ? oq : (z == 1) ? ok : ov) + (size_t)blockIdx.x * 1024;
  int c = blockIdx.x;
  int h = c >> 6, kk = c & 63;
  const float* src = W + (size_t)h * 65536 + kk;  // + d*64
  #pragma unroll
  for (int it = 0; it < 4; ++it) {
    int d = it * 256 + threadIdx.x;
    o[d] = f2bf(src[(size_t)d * 64]);
  }
}

// ------------- kernel 3: projection GEMM  C[4096][1024] = A[4096][1024] * Bt^T -------------
__global__ __launch_bounds__(256) void proj_gemm(
    const short* __restrict__ xq, const short* __restrict__ xk, const short* __restrict__ xv,
    const short* __restrict__ wq, const short* __restrict__ wk, const short* __restrict__ wv,
    short* __restrict__ pq, short* __restrict__ pk, short* __restrict__ pv) {
  int z = blockIdx.z;
  const short* A  = (z == 0) ? xq : (z == 1) ? xk : xv;
  const short* Bt = (z == 0) ? wq : (z == 1) ? wk : wv;
  short* C        = (z == 0) ? pq : (z == 1) ? pk : pv;
  __shared__ __attribute__((aligned(16))) short As[128 * 32];
  __shared__ __attribute__((aligned(16))) short Bs[128 * 32];
  int t = threadIdx.x, l = t & 63, w = t >> 6;
  int wr = w >> 1, wc = w & 1;
  int lr = l & 15, lk = l >> 4;
  int bm0 = blockIdx.y * 128, bn0 = blockIdx.x * 128;
  const f32x4 Z = {0.f, 0.f, 0.f, 0.f};
  f32x4 acc[4][4];
  #pragma unroll
  for (int m = 0; m < 4; ++m)
    #pragma unroll
    for (int n = 0; n < 4; ++n) acc[m][n] = Z;

  int r0 = t >> 2, r1 = r0 + 64;
  int s0 = (t & 3) * 8;
  const short* gA0 = A + (size_t)(bm0 + r0) * 1024 + s0;
  const short* gA1 = A + (size_t)(bm0 + r1) * 1024 + s0;
  const short* gB0 = Bt + (size_t)(bn0 + r0) * 1024 + s0;
  const short* gB1 = Bt + (size_t)(bn0 + r1) * 1024 + s0;

  for (int kb = 0; kb < 1024; kb += 32) {
    short8 a0 = *(const short8*)(gA0 + kb);
    short8 a1 = *(const short8*)(gA1 + kb);
    short8 b0 = *(const short8*)(gB0 + kb);
    short8 b1 = *(const short8*)(gB1 + kb);
    *(short8*)(As + r0 * 32 + s0) = a0;
    *(short8*)(As + r1 * 32 + s0) = a1;
    *(short8*)(Bs + r0 * 32 + s0) = b0;
    *(short8*)(Bs + r1 * 32 + s0) = b1;
    __syncthreads();
    short8 a[4], bfr[4];
    #pragma unroll
    for (int m = 0; m < 4; ++m)
      a[m] = *(const short8*)(As + (wr * 64 + m * 16 + lr) * 32 + lk * 8);
    #pragma unroll
    for (int n = 0; n < 4; ++n)
      bfr[n] = *(const short8*)(Bs + (wc * 64 + n * 16 + lr) * 32 + lk * 8);
    #pragma unroll
    for (int m = 0; m < 4; ++m)
      #pragma unroll
      for (int n = 0; n < 4; ++n)
        acc[m][n] = __builtin_amdgcn_mfma_f32_16x16x32_bf16(a[m], bfr[n], acc[m][n], 0, 0, 0);
    __syncthreads();
  }
  #pragma unroll
  for (int m = 0; m < 4; ++m)
    #pragma unroll
    for (int n = 0; n < 4; ++n)
      #pragma unroll
      for (int i = 0; i < 4; ++i) {
        int r = bm0 + wr * 64 + m * 16 + lk * 4 + i;
        int cc = bn0 + wc * 64 + n * 16 + lr;
        C[(size_t)r * 1024 + cc] = f2bf(acc[m][n][i]);
      }
}

// ------------- kernel 4: V transpose  pv[b*N+n][h*64+dv] -> vt[hb][dv][n] -------------
__global__ __launch_bounds__(256) void vtrans(
    const short* __restrict__ pv, short* __restrict__ vt) {
  __shared__ short T[64 * 72];
  int t = threadIdx.x;
  int hb = blockIdx.y, h = hb >> 2, b = hb & 3;
  int n0 = blockIdx.x * 64;
  const short* src = pv + (size_t)b * 1048576 + (size_t)n0 * 1024 + h * 64;
  #pragma unroll
  for (int it = 0; it < 2; ++it) {
    int id = it * 256 + t;
    int row = id >> 3, seg = id & 7;
    *(short8*)(T + row * 72 + seg * 8) = *(const short8*)(src + (size_t)row * 1024 + seg * 8);
  }
  __syncthreads();
  short* dst = vt + (size_t)hb * 65536 + n0;
  #pragma unroll
  for (int it = 0; it < 2; ++it) {
    int id = it * 256 + t;
    int dv = id >> 3, seg = id & 7;
    short8 vv;
    #pragma unroll
    for (int jj = 0; jj < 8; ++jj) vv[jj] = T[(seg * 8 + jj) * 72 + dv];
    *(short8*)(dst + (size_t)dv * 1024 + seg * 8) = vv;
  }
}

// ------------- kernel 5: fused attention -------------
// per block: (hb, 64 q-rows), 4 waves x 16 rows. 2-pass online softmax in regs,
// attn written f32 direct, P relayed bf16 via LDS to PV MFMA, V read from vt (L2).
#define PW 72
__global__ __launch_bounds__(256) void attn_fused(
    const short* __restrict__ pq, const short* __restrict__ pk, const short* __restrict__ vt,
    float* __restrict__ dout) {
  __shared__ __attribute__((aligned(16))) short Qs[64 * PW];
  __shared__ __attribute__((aligned(16))) short Ks[64 * PW];
  __shared__ __attribute__((aligned(16))) short Ps[64 * PW];
  int t = threadIdx.x, l = t & 63, w = t >> 6;
  int lr = l & 15, lk = l >> 4;
  int hb = blockIdx.y, h = hb >> 2, b = hb & 3;   // hb = h*B + b
  int q0 = blockIdx.x * 64;
  const short* Qg = pq + (size_t)b * 1048576 + h * 64;
  const short* Kg = pk + (size_t)b * 1048576 + h * 64;
  const short* Vt = vt + (size_t)hb * 65536;
  float* attnp = dout + 4194304 + (size_t)hb * 1048576;
  const f32x4 Z = {0.f, 0.f, 0.f, 0.f};
  const float scale = 0.125f;

  // stage Q tile [64][64]
  {
    int j = t >> 3, co = (t & 7) * 8;
    #pragma unroll
    for (int it = 0; it < 2; ++it) {
      int row = it * 32 + j;
      *(short8*)(Qs + row * PW + co) = *(const short8*)(Qg + (size_t)(q0 + row) * 1024 + co);
    }
  }
  __syncthreads();
  int r0 = w * 16;
  short8 aq[2];
  aq[0] = *(const short8*)(Qs + (r0 + lr) * PW + lk * 8);
  aq[1] = *(const short8*)(Qs + (r0 + lr) * PW + 32 + lk * 8);

  float m[4], s[4];
  #pragma unroll
  for (int i = 0; i < 4; ++i) { m[i] = -1e30f; s[i] = 0.0f; }

  // ---- pass 1: per-lane online (max, sumexp) ----
  for (int nc = 0; nc < 16; ++nc) {
    {
      int j = t >> 3, co = (t & 7) * 8;
      #pragma unroll
      for (int it = 0; it < 2; ++it) {
        int row = it * 32 + j;
        *(short8*)(Ks + row * PW + co) = *(const short8*)(Kg + (size_t)(nc * 64 + row) * 1024 + co);
      }
    }
    __syncthreads();
    f32x4 acc[4] = {Z, Z, Z, Z};
    #pragma unroll
    for (int kk = 0; kk < 2; ++kk)
      #pragma unroll
      for (int n = 0; n < 4; ++n) {
        short8 bk = *(const short8*)(Ks + (n * 16 + lr) * PW + kk * 32 + lk * 8);
        acc[n] = __builtin_amdgcn_mfma_f32_16x16x32_bf16(aq[kk], bk, acc[n], 0, 0, 0);
      }
    #pragma unroll
    for (int i = 0; i < 4; ++i) {
      float sv0 = acc[0][i] * scale, sv1 = acc[1][i] * scale;
      float sv2 = acc[2][i] * scale, sv3 = acc[3][i] * scale;
      float cm = fmaxf(fmaxf(sv0, sv1), fmaxf(sv2, sv3));
      float nm = fmaxf(m[i], cm);
      float cs = __expf(sv0 - nm) + __expf(sv1 - nm) + __expf(sv2 - nm) + __expf(sv3 - nm);
      s[i] = s[i] * __expf(m[i] - nm) + cs;
      m[i] = nm;
    }
    __syncthreads();
  }
  // butterfly-combine (m,s) across the 16 lanes of each row group
  #pragma unroll
  for (int i = 0; i < 4; ++i) {
    #pragma unroll
    for (int msk = 1; msk < 16; msk <<= 1) {
      float om = __shfl_xor(m[i], msk, 64);
      float os = __shfl_xor(s[i], msk, 64);
      float nm = fmaxf(m[i], om);
      s[i] = s[i] * __expf(m[i] - nm) + os * __expf(om - nm);
      m[i] = nm;
    }
  }
  float inv[4];
  #pragma unroll
  for (int i = 0; i < 4; ++i) inv[i] = 1.0f / s[i];

  // ---- pass 2: recompute S, write attn f32, P->LDS bf16, PV from vt ----
  f32x4 acco[4] = {Z, Z, Z, Z};
  for (int nc = 0; nc < 16; ++nc) {
    {
      int j = t >> 3, co = (t & 7) * 8;
      #pragma unroll
      for (int it = 0; it < 2; ++it) {
        int row = it * 32 + j;
        *(short8*)(Ks + row * PW + co) = *(const short8*)(Kg + (size_t)(nc * 64 + row) * 1024 + co);
      }
    }
    __syncthreads();
    f32x4 acc[4] = {Z, Z, Z, Z};
    #pragma unroll
    for (int kk = 0; kk < 2; ++kk)
      #pragma unroll
      for (int n = 0; n < 4; ++n) {
        short8 bk = *(const short8*)(Ks + (n * 16 + lr) * PW + kk * 32 + lk * 8);
        acc[n] = __builtin_amdgcn_mfma_f32_16x16x32_bf16(aq[kk], bk, acc[n], 0, 0, 0);
      }
    // normalized P -> attn (f32, direct) and Ps (bf16, wave-private rows)
    #pragma unroll
    for (int n = 0; n < 4; ++n)
      #pragma unroll
      for (int i = 0; i < 4; ++i) {
        float p = __expf(acc[n][i] * scale - m[i]) * inv[i];
        Ps[(r0 + lk * 4 + i) * PW + n * 16 + lr] = f2bf(p);
        attnp[(size_t)(q0 + r0 + lk * 4 + i) * 1024 + nc * 64 + n * 16 + lr] = p;
      }
    // PV: acco += P * V  (A = Ps rows, B = vt rows from global/L2)
    #pragma unroll
    for (int kk = 0; kk < 2; ++kk) {
      short8 ap = *(const short8*)(Ps + (r0 + lr) * PW + kk * 32 + lk * 8);
      #pragma unroll
      for (int f = 0; f < 4; ++f) {
        short8 bv = *(const short8*)(Vt + (size_t)(f * 16 + lr) * 1024 + nc * 64 + kk * 32 + lk * 8);
        acco[f] = __builtin_amdgcn_mfma_f32_16x16x32_bf16(ap, bv, acco[f], 0, 0, 0);
      }
    }
    __syncthreads();
  }
  // out[b][n][h*64+dv] (f32)
  #pragma unroll
  for (int f = 0; f < 4; ++f)
    #pragma unroll
    for (int i = 0; i < 4; ++i) {
      int row = q0 + r0 + lk * 4 + i;
      int dv = f * 16 + lr;
      dout[(size_t)b * 1048576 + (size_t)row * 1024 + h * 64 + dv] = acco[f][i];
    }
}

extern "C" void kernel_launch(void* const* d_in, const int* in_sizes, int n_in,
                              void* d_out, int out_size, void* d_ws, size_t ws_size,
                              hipStream_t stream) {
  const void* big[3] = {0, 0, 0};
  const void* small[3] = {0, 0, 0};
  int nb = 0, ns = 0;
  for (int i = 0; i < n_in && i < 6; ++i) {
    if (in_sizes[i] == 4194304) { if (nb < 3) big[nb++] = d_in[i]; }
    else                        { if (ns < 3) small[ns++] = d_in[i]; }
  }
  const float *q, *k, *v, *wq, *wk, *wv;
  if (nb == 3 && ns == 3) {
    q = (const float*)big[0]; k = (const float*)big[1]; v = (const float*)big[2];
    wq = (const float*)small[0]; wk = (const float*)small[1]; wv = (const float*)small[2];
  } else {
    q = (const float*)d_in[0]; k = (const float*)d_in[1]; v = (const float*)d_in[2];
    wq = (const float*)d_in[3]; wk = (const float*)d_in[4]; wv = (const float*)d_in[5];
  }
  short* W   = (short*)d_ws;
  short* xq  = W;
  short* xk  = W + 4194304;
  short* xv  = W + 8388608;
  short* wtq = W + 12582912;
  short* wtk = W + 13631488;
  short* wtv = W + 14680064;
  short* pq  = W + 15728640;
  short* pk  = W + 19922944;
  short* pv  = W + 24117248;
  short* vt  = W + 28311552;
  float* out = (float*)d_out;

  cast_qkv<<<dim3(4096, 1, 3), 256, 0, stream>>>(q, k, v, xq, xk, xv);
  pack_w<<<dim3(1024, 1, 3), 256, 0, stream>>>(wq, wk, wv, wtq, wtk, wtv);
  proj_gemm<<<dim3(8, 32, 3), 256, 0, stream>>>(xq, xk, xv, wtq, wtk, wtv, pq, pk, pv);
  vtrans<<<dim3(16, 64), 256, 0, stream>>>(pv, vt);
  attn_fused<<<dim3(16, 64), 256, 0, stream>>>(pq, pk, vt, out);
}